// Round 12
// baseline (199.779 us; speedup 1.0000x reference)
//
#include <hip/hip_runtime.h>

// Bidirectional GRU (H=32, input=1, B=2048, T=512) + MLP head, fully fused.
//
// Reference takes out[:, -1, :] = concat(h_fwd after T steps, h_bwd after ONE
// step from h0=0 on x[T-1]) -> only the forward scan is sequential; W_hh_b is
// entirely unused.
//
// R23 = R21 (best: 86.1 us; MFMA recurrence, pair-layout LDS exchange) with
// TWO independent row-groups per wave, software-interleaved.
//
// Chain ledger (R21, closes at 403 cyc/step): DS write->read roundtrip ~240
// (in-order DS pipe) + MFMA pipe ~96 + trans chain ~76 + glue. R12/R20:
// crossbars don't beat LDS. A single wave can't overlap its own serial
// chain -- but two INDEPENDENT chains interleave: while stream A waits on
// its DS roundtrip, the SIMD issues stream B's MFMAs/epilogue.
//
//   * Each 64-lane wave serves group A (rows 4w,4w+1) and group B (rows
//     4w+2,4w+3), R21 body duplicated+interleaved. No cross-wave coupling.
//   * SHARED between streams: B-frags (W_hh, 24 VGPR), per-lane seed consts
//     (same j). Doubled: x, h, A-frag, exchange slots (hp gid = 2*wid+grp).
//   * R22 regressions reverted: xbuf staging restored, R21 MFMA order
//     (Dr,Dz,Dn) and R21 epilogue order (z-path first, fused tail) restored.
//   * 256 blocks x 128 thr (2 waves/block) = 512 waves, ~0.5/SIMD --
//     irrelevant: latency-bound, all 2048 rows advance concurrently.
//   * Exchange per stream unchanged: packed-pair buffer, one ds_write_b16 +
//     one broadcast ds_read_b128 (B pair-interleaved labeling), parity dbuf.

typedef float vf4 __attribute__((ext_vector_type(4)));
typedef _Float16 f16;
typedef f16 h8 __attribute__((ext_vector_type(8)));

#define TT 512
#define HH 32

#define LOG2E 1.44269504f

__device__ __forceinline__ float fast_sigm(float a) {   // sigmoid(a)
  return __builtin_amdgcn_rcpf(1.0f + __builtin_amdgcn_exp2f(-LOG2E * a));
}
__device__ __forceinline__ float fast_tanh(float a) {   // tanh(a)
  return __builtin_fmaf(-2.0f,
      __builtin_amdgcn_rcpf(1.0f + __builtin_amdgcn_exp2f(2.0f * LOG2E * a)),
      1.0f);
}

__global__ __launch_bounds__(128)
__attribute__((amdgpu_waves_per_eu(1, 1)))
void gru_bidir_head(const float* __restrict__ X,
                    const float* __restrict__ Wih_f, const float* __restrict__ Whh_f,
                    const float* __restrict__ bih_f, const float* __restrict__ bhh_f,
                    const float* __restrict__ Wih_b,
                    const float* __restrict__ bih_b, const float* __restrict__ bhh_b,
                    const float* __restrict__ W1, const float* __restrict__ b1,
                    const float* __restrict__ W2, const float* __restrict__ b2,
                    float* __restrict__ out)
{
  __shared__ float    xbuf[8][TT];       // staged input rows (16 KB)
  __shared__ unsigned hp[2][4][2][16];   // packed-pair h exchange, dbuf (1 KB)
  __shared__ float    obuf[8][64];       // [row][h_f(32) | h_b(32)] (2 KB)

  const int tid  = threadIdx.x;
  const int lane = tid & 63;
  const int wid  = tid >> 6;           // wave 0..1; serves block rows 4wid..4wid+3
  const int nh   = lane & 15;          // MFMA n-index
  const int q    = lane >> 4;          // quad 0..3
  const int p    = q & 1;              // owned element's row parity
  const int hsel = lane >> 5;          // owned element's j-half
  const int j    = nh + 16 * hsel;     // owned output column
  const int rowb = (blockIdx.x << 3);  // block's global base row
  const int rsA  = 4 * wid + p;        // stream A: owned local row
  const int rsB  = 4 * wid + 2 + p;    // stream B: owned local row

  // --- stage 8 rows of X into LDS (contiguous 4096 floats, grid-stride) ---
  {
    const vf4* src = (const vf4*)(X + (size_t)rowb * TT);
    vf4* dst = (vf4*)&xbuf[0][0];
    #pragma unroll
    for (int i = 0; i < 8; ++i) dst[tid + 128 * i] = src[tid + 128 * i];
  }

  const float s1 = -LOG2E;             // r,z: sigmoid domain (negated)
  const float s2 = 2.0f * LOG2E;       // n: tanh domain

  // --- B-fragments: W_hh, constant, PAIR-INTERLEAVED labeling (R20-proven):
  //     element order k = (4q, 16+4q, 4q+1, 16+4q+1, ...). Shared by streams.
#define LDB(P, G, F, S) h8 P; { \
    const float* wr = Whh_f + (size_t)((G)*HH + nh + 16*(F)) * HH; \
    const int k1 = 4*q, k2 = 16 + 4*q; \
    P = (h8){ (f16)(wr[k1  ]*(S)), (f16)(wr[k2  ]*(S)), \
              (f16)(wr[k1+1]*(S)), (f16)(wr[k2+1]*(S)), \
              (f16)(wr[k1+2]*(S)), (f16)(wr[k2+2]*(S)), \
              (f16)(wr[k1+3]*(S)), (f16)(wr[k2+3]*(S)) }; }
  LDB(Br0, 0, 0, s1); LDB(Br1, 0, 1, s1);
  LDB(Bz0, 1, 0, s1); LDB(Bz1, 1, 1, s1);
  LDB(Bn0, 2, 0, s2); LDB(Bn1, 2, 1, s2);

  // --- per-lane seed consts for the owned column j (shared by streams) ---
  const float xwr = Wih_f[j] * s1, xwz = Wih_f[HH + j] * s1, xwn = Wih_f[2*HH + j] * s2;
  const float cbr = (bih_f[j]      + bhh_f[j])      * s1;
  const float cbz = (bih_f[HH + j] + bhh_f[HH + j]) * s1;
  const float cbn = bih_f[2*HH + j] * s2;        // n: b_ih term (with x)
  const float cbh = bhh_f[2*HH + j] * s2;        // n: b_hh term (inside r*(.)) -> C
  const vf4 Ch = { cbh, 0.0f, 0.0f, 0.0f };

  // --- exchange addresses per stream (loop-invariant) ---
  const int Rr   = (lane >> 2) & 1;
  const int gidA = (wid << 1);
  const int gidB = (wid << 1) | 1;
  const h8* rpA0 = (const h8*)&hp[0][gidA][Rr][q << 2];
  const h8* rpA1 = (const h8*)&hp[1][gidA][Rr][q << 2];
  const h8* rpB0 = (const h8*)&hp[0][gidB][Rr][q << 2];
  const h8* rpB1 = (const h8*)&hp[1][gidB][Rr][q << 2];
  unsigned short* wpA0 = (unsigned short*)&hp[0][gidA][p][nh] + hsel;
  unsigned short* wpA1 = (unsigned short*)&hp[1][gidA][p][nh] + hsel;
  unsigned short* wpB0 = (unsigned short*)&hp[0][gidB][p][nh] + hsel;
  unsigned short* wpB1 = (unsigned short*)&hp[1][gidB][p][nh] + hsel;

  float hA = 0.0f, hB = 0.0f;
  *wpA0 = 0; *wpA1 = 0; *wpB0 = 0; *wpB1 = 0;    // h0 = 0, both parities
  __syncthreads();                               // x staged + hp init

  const vf4* xvA = (const vf4*)&xbuf[rsA][0];
  const vf4* xvB = (const vf4*)&xbuf[rsB][0];
  vf4 x4A = xvA[0], x4B = xvB[0];

  #pragma unroll 1
  for (int tg = 0; tg < TT / 4; ++tg) {
    const int tgn = tg + 1 < TT / 4 ? tg + 1 : tg;
    const vf4 x4An = xvA[tgn], x4Bn = xvB[tgn];  // off critical path

    // hoist x-dependent seeds for the 4 sub-steps, both streams
#define SEEDS(S_, X_) \
    const float sr0##S_ = __builtin_fmaf((X_).x, xwr, cbr), sz0##S_ = __builtin_fmaf((X_).x, xwz, cbz), \
                sn0##S_ = __builtin_fmaf((X_).x, xwn, cbn); \
    const float sr1##S_ = __builtin_fmaf((X_).y, xwr, cbr), sz1##S_ = __builtin_fmaf((X_).y, xwz, cbz), \
                sn1##S_ = __builtin_fmaf((X_).y, xwn, cbn); \
    const float sr2##S_ = __builtin_fmaf((X_).z, xwr, cbr), sz2##S_ = __builtin_fmaf((X_).z, xwz, cbz), \
                sn2##S_ = __builtin_fmaf((X_).z, xwn, cbn); \
    const float sr3##S_ = __builtin_fmaf((X_).w, xwr, cbr), sz3##S_ = __builtin_fmaf((X_).w, xwz, cbz), \
                sn3##S_ = __builtin_fmaf((X_).w, xwn, cbn)
    SEEDS(A, x4A);
    SEEDS(B, x4B);

    #pragma unroll
    for (int u = 0; u < 4; ++u) {
      const float srA = (u == 0) ? sr0A : (u == 1) ? sr1A : (u == 2) ? sr2A : sr3A;
      const float szA = (u == 0) ? sz0A : (u == 1) ? sz1A : (u == 2) ? sz2A : sz3A;
      const float snA = (u == 0) ? sn0A : (u == 1) ? sn1A : (u == 2) ? sn2A : sn3A;
      const float srB = (u == 0) ? sr0B : (u == 1) ? sr1B : (u == 2) ? sr2B : sr3B;
      const float szB = (u == 0) ? sz0B : (u == 1) ? sz1B : (u == 2) ? sz2B : sz3B;
      const float snB = (u == 0) ? sn0B : (u == 1) ? sn1B : (u == 2) ? sn2B : sn3B;

      // A-frags: one broadcast ds_read_b128 per stream (parity u&1)
      const h8 AA = (u & 1) ? *rpA1 : *rpA0;
      const h8 AB = (u & 1) ? *rpB1 : *rpB0;

      // D = h @ W^T (+ seeds in C reg0): 6 MFMA per stream, R21 order
      const vf4 CrA = { srA, 0.0f, 0.0f, 0.0f };
      const vf4 CzA = { szA, 0.0f, 0.0f, 0.0f };
      const vf4 CrB = { srB, 0.0f, 0.0f, 0.0f };
      const vf4 CzB = { szB, 0.0f, 0.0f, 0.0f };
      const vf4 DrA0 = __builtin_amdgcn_mfma_f32_16x16x32_f16(AA, Br0, CrA, 0, 0, 0);
      const vf4 DrA1 = __builtin_amdgcn_mfma_f32_16x16x32_f16(AA, Br1, CrA, 0, 0, 0);
      const vf4 DzA0 = __builtin_amdgcn_mfma_f32_16x16x32_f16(AA, Bz0, CzA, 0, 0, 0);
      const vf4 DzA1 = __builtin_amdgcn_mfma_f32_16x16x32_f16(AA, Bz1, CzA, 0, 0, 0);
      const vf4 DnA0 = __builtin_amdgcn_mfma_f32_16x16x32_f16(AA, Bn0, Ch, 0, 0, 0);
      const vf4 DnA1 = __builtin_amdgcn_mfma_f32_16x16x32_f16(AA, Bn1, Ch, 0, 0, 0);
      const vf4 DrB0 = __builtin_amdgcn_mfma_f32_16x16x32_f16(AB, Br0, CrB, 0, 0, 0);
      const vf4 DrB1 = __builtin_amdgcn_mfma_f32_16x16x32_f16(AB, Br1, CrB, 0, 0, 0);
      const vf4 DzB0 = __builtin_amdgcn_mfma_f32_16x16x32_f16(AB, Bz0, CzB, 0, 0, 0);
      const vf4 DzB1 = __builtin_amdgcn_mfma_f32_16x16x32_f16(AB, Bz1, CzB, 0, 0, 0);
      const vf4 DnB0 = __builtin_amdgcn_mfma_f32_16x16x32_f16(AB, Bn0, Ch, 0, 0, 0);
      const vf4 DnB1 = __builtin_amdgcn_mfma_f32_16x16x32_f16(AB, Bn1, Ch, 0, 0, 0);

      // epilogue stream A (R21 order: z-path first, fused tail)
      {
        const float ar = hsel ? DrA1[0] : DrA0[0];
        const float az = hsel ? DzA1[0] : DzA0[0];
        const float an = hsel ? DnA1[0] : DnA0[0];
        const float z    = __builtin_amdgcn_rcpf(1.0f + __builtin_amdgcn_exp2f(az));
        const float omz  = 1.0f - z;
        const float base = __builtin_fmaf(z, hA, omz);       // z*h + (1-z)
        const float m2   = __builtin_fmaf(2.0f, z, -2.0f);   // -2*(1-z)
        const float r    = __builtin_amdgcn_rcpf(1.0f + __builtin_amdgcn_exp2f(ar));
        const float y    = __builtin_fmaf(r, an, snA);
        const float w    = __builtin_amdgcn_rcpf(1.0f + __builtin_amdgcn_exp2f(y));
        hA = __builtin_fmaf(m2, w, base);  // (1-z)*(1-2w) + z*h
        union { f16 f; unsigned short u16; } cc; cc.f = (f16)hA;
        if (u & 1) *wpA0 = cc.u16; else *wpA1 = cc.u16;
      }
      // epilogue stream B
      {
        const float ar = hsel ? DrB1[0] : DrB0[0];
        const float az = hsel ? DzB1[0] : DzB0[0];
        const float an = hsel ? DnB1[0] : DnB0[0];
        const float z    = __builtin_amdgcn_rcpf(1.0f + __builtin_amdgcn_exp2f(az));
        const float omz  = 1.0f - z;
        const float base = __builtin_fmaf(z, hB, omz);
        const float m2   = __builtin_fmaf(2.0f, z, -2.0f);
        const float r    = __builtin_amdgcn_rcpf(1.0f + __builtin_amdgcn_exp2f(ar));
        const float y    = __builtin_fmaf(r, an, snB);
        const float w    = __builtin_amdgcn_rcpf(1.0f + __builtin_amdgcn_exp2f(y));
        hB = __builtin_fmaf(m2, w, base);
        union { f16 f; unsigned short u16; } cc; cc.f = (f16)hB;
        if (u & 1) *wpB0 = cc.u16; else *wpB1 = cc.u16;
      }
      __builtin_amdgcn_wave_barrier();   // wave-synchronous ordering
    }
    x4A = x4An; x4B = x4Bn;
  }

  // --- publish h_f (fp32): each lane writes its (row, j) element, both streams ---
  obuf[rsA][j] = hA;
  obuf[rsB][j] = hB;
  __syncthreads();

  // --- backward (ONE GRU step from h0=0 on x[T-1]) + MLP head, per row ---
  const int g32 = tid & 31;
  const int grp = tid >> 5;              // 4 groups of 32 lanes
  #pragma unroll 1
  for (int it = 0; it < 2; ++it) {
    const int row = grp + 4 * it;
    const float xl  = xbuf[row][TT - 1];
    const float rbv = fast_sigm(__builtin_fmaf(xl, Wih_b[g32],      bih_b[g32]      + bhh_b[g32]));
    const float zbv = fast_sigm(__builtin_fmaf(xl, Wih_b[HH + g32], bih_b[HH + g32] + bhh_b[HH + g32]));
    const float xnb = __builtin_fmaf(xl, Wih_b[2*HH + g32], bih_b[2*HH + g32]);
    const float nbv = fast_tanh(__builtin_fmaf(rbv, bhh_b[2*HH + g32], xnb));
    const float hbv = nbv - zbv * nbv;   // (1-zb)*nb + zb*0
    obuf[row][32 + g32] = hbv;
    __builtin_amdgcn_wave_barrier();

    const int jj = g32 & 15;             // lanes 16..31 duplicate
    const vf4* W1r = (const vf4*)(W1 + jj * 64);
    const vf4* hc  = (const vf4*)&obuf[row][0];
    vf4 a4 = W1r[0] * hc[0];
    #pragma unroll
    for (int qq = 1; qq < 16; ++qq)
      a4 = __builtin_elementwise_fma(W1r[qq], hc[qq], a4);
    float acc = b1[jj] + (a4.x + a4.y) + (a4.z + a4.w);
    float h1v = fmaxf(acc, 0.0f) * W2[jj];
    h1v += __shfl_down(h1v, 8, 16);
    h1v += __shfl_down(h1v, 4, 16);
    h1v += __shfl_down(h1v, 2, 16);
    h1v += __shfl_down(h1v, 1, 16);
    if (g32 == 0) out[rowb + row] = fast_sigm(h1v + b2[0]);
  }
}

extern "C" void kernel_launch(void* const* d_in, const int* in_sizes, int n_in,
                              void* d_out, int out_size, void* d_ws, size_t ws_size,
                              hipStream_t stream) {
  const float* X     = (const float*)d_in[0];
  const float* Wih_f = (const float*)d_in[1];
  const float* Whh_f = (const float*)d_in[2];
  const float* bih_f = (const float*)d_in[3];
  const float* bhh_f = (const float*)d_in[4];
  const float* Wih_b = (const float*)d_in[5];
  // d_in[6] = W_hh_b: unused — backward direction runs exactly one step from h0=0.
  const float* bih_b = (const float*)d_in[7];
  const float* bhh_b = (const float*)d_in[8];
  const float* W1    = (const float*)d_in[9];
  const float* b1    = (const float*)d_in[10];
  const float* W2    = (const float*)d_in[11];
  const float* b2    = (const float*)d_in[12];
  float* out = (float*)d_out;

  // 2048 rows / 8 rows per 128-thread block = 256 blocks (2 waves/block).
  // Each wave serves TWO independent 2-row streams, software-interleaved:
  // stream A's DS roundtrip hides under stream B's MFMA+epilogue issue.
  gru_bidir_head<<<256, 128, 0, stream>>>(X, Wih_f, Whh_f, bih_f, bhh_f,
                                          Wih_b, bih_b, bhh_b, W1, b1, W2, b2, out);
}